// Round 4
// baseline (904.387 us; speedup 1.0000x reference)
//
#include <hip/hip_runtime.h>
#include <math.h>

#define HID 64
#define KIN 512

// ============ no-barrier split-K GEMM building block ============
// Block = 128 thr (2 waves), tile = 64 nodes x 64 cols.
// Each wave owns HALF of K with private LDS chunks (16k x 64) -> no
// __syncthreads in the main loop. 8x8 micro-tile per lane
// (64 FMA : 4 ds_read_b128). XOR swizzle k*64 + (n ^ ((k>>2)<<4)):
// staging b32 writes 2-way (free), fragment b128 reads 2-way (free).
// Register prefetch of next chunk overlaps HBM latency with compute.

// ---------------- encoder: h = x @ W_enc + b_enc ----------------
__global__ __launch_bounds__(128) void enc_kernel(
    const float* __restrict__ x, const float* __restrict__ W,
    const float* __restrict__ b, float* __restrict__ h, int N) {
  __shared__ float smem[4160];  // main: 2x(xs 1024 + ws 1024); reduce: 64x65
  const int tid = threadIdx.x;
  const int lane = tid & 63;
  const int wid = tid >> 6;
  const int ng = lane >> 3;
  const int cg = lane & 7;
  const int blockBase = blockIdx.x * 64;
  float* xsW = smem + wid * 1024;
  float* wsW = smem + 2048 + wid * 1024;
  const int kBase = wid * 256;  // this wave's K range: 256 of 512

  float acc[8][8];
#pragma unroll
  for (int i = 0; i < 8; i++)
#pragma unroll
    for (int j = 0; j < 8; j++) acc[i][j] = 0.f;

  const int kq = lane & 3;        // x f4-slot within 16k chunk
  const int nrow = lane >> 2;     // x node sub-row (0..15, +16*i)
  const int wrow = lane >> 4;     // W sub-row (0..3, +4*i)
  const int wc4 = lane & 15;      // W f4-col

  float4 px[4], pw[4];
  // prefetch chunk 0
  {
    const int kb = kBase;
#pragma unroll
    for (int i = 0; i < 4; i++) {
      const int gn = blockBase + i * 16 + nrow;
      px[i] = (gn < N) ? *(const float4*)(x + (size_t)gn * KIN + kb + kq * 4)
                       : make_float4(0.f, 0.f, 0.f, 0.f);
      pw[i] = *(const float4*)(W + (size_t)(kb + i * 4 + wrow) * HID + wc4 * 4);
    }
  }

  for (int kc = 0; kc < 16; kc++) {
    // store staged regs -> private LDS (swizzled transpose for x)
#pragma unroll
    for (int i = 0; i < 4; i++) {
      const int nl = i * 16 + nrow;
      const int m = kq * 16;  // ((k>>2)<<4), k = kq*4+c
      xsW[(kq * 4 + 0) * 64 + (nl ^ m)] = px[i].x;
      xsW[(kq * 4 + 1) * 64 + (nl ^ m)] = px[i].y;
      xsW[(kq * 4 + 2) * 64 + (nl ^ m)] = px[i].z;
      xsW[(kq * 4 + 3) * 64 + (nl ^ m)] = px[i].w;
      ((float4*)wsW)[lane + i * 64] = pw[i];
    }
    // issue next chunk's global loads (overlap with compute below)
    if (kc < 15) {
      const int kb = kBase + (kc + 1) * 16;
#pragma unroll
      for (int i = 0; i < 4; i++) {
        const int gn = blockBase + i * 16 + nrow;
        px[i] = (gn < N)
                    ? *(const float4*)(x + (size_t)gn * KIN + kb + kq * 4)
                    : make_float4(0.f, 0.f, 0.f, 0.f);
        pw[i] =
            *(const float4*)(W + (size_t)(kb + i * 4 + wrow) * HID + wc4 * 4);
      }
    }
    // compute 16 k-steps
#pragma unroll
    for (int k = 0; k < 16; k++) {
      const int sw = (k & 12) << 2;
      const float4 a0 = *(const float4*)&xsW[k * 64 + ((ng * 8) ^ sw)];
      const float4 a1 = *(const float4*)&xsW[k * 64 + ((ng * 8 + 4) ^ sw)];
      const float4 b0 = *(const float4*)&wsW[k * 64 + cg * 8];
      const float4 b1 = *(const float4*)&wsW[k * 64 + cg * 8 + 4];
      const float av[8] = {a0.x, a0.y, a0.z, a0.w, a1.x, a1.y, a1.z, a1.w};
      const float bv[8] = {b0.x, b0.y, b0.z, b0.w, b1.x, b1.y, b1.z, b1.w};
#pragma unroll
      for (int i = 0; i < 8; i++)
#pragma unroll
        for (int j = 0; j < 8; j++) acc[i][j] += av[i] * bv[j];
    }
  }

  // cross-wave accumulator merge (the only barriers in the kernel)
  __syncthreads();
  if (wid == 1) {
#pragma unroll
    for (int i = 0; i < 8; i++)
#pragma unroll
      for (int j = 0; j < 8; j++) smem[lane * 65 + i * 8 + j] = acc[i][j];
  }
  __syncthreads();
  if (wid == 0) {
    float bj[8];
#pragma unroll
    for (int j = 0; j < 8; j++) bj[j] = b[cg * 8 + j];
#pragma unroll
    for (int i = 0; i < 8; i++) {
      const int n = blockBase + ng * 8 + i;
      if (n < N) {
        float4 o0, o1;
        o0.x = acc[i][0] + smem[lane * 65 + i * 8 + 0] + bj[0];
        o0.y = acc[i][1] + smem[lane * 65 + i * 8 + 1] + bj[1];
        o0.z = acc[i][2] + smem[lane * 65 + i * 8 + 2] + bj[2];
        o0.w = acc[i][3] + smem[lane * 65 + i * 8 + 3] + bj[3];
        o1.x = acc[i][4] + smem[lane * 65 + i * 8 + 4] + bj[4];
        o1.y = acc[i][5] + smem[lane * 65 + i * 8 + 5] + bj[5];
        o1.z = acc[i][6] + smem[lane * 65 + i * 8 + 6] + bj[6];
        o1.w = acc[i][7] + smem[lane * 65 + i * 8 + 7] + bj[7];
        *(float4*)(h + (size_t)n * HID + cg * 8) = o0;
        *(float4*)(h + (size_t)n * HID + cg * 8 + 4) = o1;
      }
    }
  }
}

// ---------------- degree histogram ----------------
__global__ void hist_kernel(const int* __restrict__ dst, int* __restrict__ cnt,
                            int E, int N) {
  int e = blockIdx.x * blockDim.x + threadIdx.x;
  if (e < E) {
    int d = dst[e];
    if ((unsigned)d < (unsigned)N) atomicAdd(&cnt[d], 1);
  }
}

// ---------------- parallel scan: phase A (block sums) ----------------
__global__ __launch_bounds__(1024) void scanA_kernel(
    const int* __restrict__ cnt, int* __restrict__ block_sums, int N) {
  __shared__ int red[1024];
  const int tid = threadIdx.x;
  const int i = blockIdx.x * 1024 + tid;
  red[tid] = (i < N) ? cnt[i] : 0;
  __syncthreads();
  for (int off = 512; off > 0; off >>= 1) {
    if (tid < off) red[tid] += red[tid + off];
    __syncthreads();
  }
  if (tid == 0) block_sums[blockIdx.x] = red[0];
}

// ---------------- phase B: scan block sums (single block) ----------------
__global__ __launch_bounds__(128) void scanB_kernel(
    int* __restrict__ block_sums, int* __restrict__ row_start, int nblk,
    int N) {
  __shared__ int part[128];
  const int tid = threadIdx.x;
  part[tid] = (tid < nblk) ? block_sums[tid] : 0;
  __syncthreads();
  for (int off = 1; off < 128; off <<= 1) {
    int t = (tid >= off) ? part[tid - off] : 0;
    __syncthreads();
    part[tid] += t;
    __syncthreads();
  }
  if (tid < nblk) block_sums[tid] = (tid > 0) ? part[tid - 1] : 0;  // exclusive
  if (tid == 127) row_start[N] = part[127];
}

// ---------------- phase C: local scan + apply offset ----------------
__global__ __launch_bounds__(1024) void scanC_kernel(
    const int* __restrict__ cnt, const int* __restrict__ block_sums,
    int* __restrict__ row_start, float* __restrict__ inv_deg, int N) {
  __shared__ int part[1024];
  const int tid = threadIdx.x;
  const int i = blockIdx.x * 1024 + tid;
  const int v = (i < N) ? cnt[i] : 0;
  part[tid] = v;
  __syncthreads();
  for (int off = 1; off < 1024; off <<= 1) {
    int t = (tid >= off) ? part[tid - off] : 0;
    __syncthreads();
    part[tid] += t;
    __syncthreads();
  }
  if (i < N) {
    row_start[i] = block_sums[blockIdx.x] + part[tid] - v;  // exclusive
    inv_deg[i] = (v > 0) ? 1.0f / (float)v : 0.0f;
  }
}

// ---------------- bucket edges by dst (CSR) ----------------
__global__ void scatter_kernel(const int* __restrict__ src,
                               const int* __restrict__ dst,
                               const int* __restrict__ row_start,
                               int* __restrict__ cursor,
                               int* __restrict__ csr_src, int E, int N) {
  int e = blockIdx.x * blockDim.x + threadIdx.x;
  if (e < E) {
    int d = dst[e];
    if ((unsigned)d < (unsigned)N) {
      int pos = row_start[d] + atomicAdd(&cursor[d], 1);
      int s = src[e];
      if ((unsigned)s >= (unsigned)N) s = 0;
      csr_src[pos] = s;
    }
  }
}

// ---------------- mean aggregation ----------------
// one wave per node; lane = (edge-subgroup 0..3, float4-idx 0..15).
__global__ __launch_bounds__(256) void agg_kernel(
    const float* __restrict__ h, const int* __restrict__ row_start,
    const int* __restrict__ csr_src, const float* __restrict__ inv_deg,
    float* __restrict__ agg, int N) {
  const int gw = (int)((blockIdx.x * (size_t)blockDim.x + threadIdx.x) >> 6);
  const int lane = threadIdx.x & 63;
  if (gw >= N) return;
  const int sub = lane >> 4;
  const int fq = lane & 15;
  const int s = row_start[gw];
  const int e = row_start[gw + 1];
  float4 acc = make_float4(0.f, 0.f, 0.f, 0.f);
  for (int i = s; i < e; i += 4) {
    const int ei = i + sub;
    if (ei < e) {
      const int n = csr_src[ei];
      const float4 v = *(const float4*)(h + (size_t)n * HID + fq * 4);
      acc.x += v.x;
      acc.y += v.y;
      acc.z += v.z;
      acc.w += v.w;
    }
  }
#pragma unroll
  for (int off = 32; off >= 16; off >>= 1) {
    acc.x += __shfl_down(acc.x, off, 64);
    acc.y += __shfl_down(acc.y, off, 64);
    acc.z += __shfl_down(acc.z, off, 64);
    acc.w += __shfl_down(acc.w, off, 64);
  }
  if (sub == 0) {
    const float id = inv_deg[gw];
    float4 o;
    o.x = acc.x * id;
    o.y = acc.y * id;
    o.z = acc.z * id;
    o.w = acc.w * id;
    *(float4*)(agg + (size_t)gw * HID + fq * 4) = o;
  }
}

// -------- layer update: h = relu(h + agg@Wl + bl + h@Wr) --------
// Split-K as [agg | h] @ [Wl ; Wr]: wave0 does agg@Wl, wave1 does h@Wr.
__global__ __launch_bounds__(128) void update_kernel(
    float* __restrict__ h, const float* __restrict__ agg,
    const float* __restrict__ Wl, const float* __restrict__ bl,
    const float* __restrict__ Wr, int N) {
  __shared__ float smem[4160];
  const int tid = threadIdx.x;
  const int lane = tid & 63;
  const int wid = tid >> 6;
  const int ng = lane >> 3;
  const int cg = lane & 7;
  const int blockBase = blockIdx.x * 64;
  float* xsW = smem + wid * 1024;
  float* wsW = smem + 2048 + wid * 1024;
  const float* __restrict__ srcM = wid ? h : agg;
  const float* __restrict__ Wsrc = wid ? Wr : Wl;

  float acc[8][8];
#pragma unroll
  for (int i = 0; i < 8; i++)
#pragma unroll
    for (int j = 0; j < 8; j++) acc[i][j] = 0.f;

  const int kq = lane & 3;
  const int nrow = lane >> 2;
  const int wrow = lane >> 4;
  const int wc4 = lane & 15;

  float4 px[4], pw[4];
  {
#pragma unroll
    for (int i = 0; i < 4; i++) {
      const int gn = blockBase + i * 16 + nrow;
      px[i] = (gn < N)
                  ? *(const float4*)(srcM + (size_t)gn * HID + kq * 4)
                  : make_float4(0.f, 0.f, 0.f, 0.f);
      pw[i] = *(const float4*)(Wsrc + (size_t)(i * 4 + wrow) * HID + wc4 * 4);
    }
  }

  for (int kc = 0; kc < 4; kc++) {
#pragma unroll
    for (int i = 0; i < 4; i++) {
      const int nl = i * 16 + nrow;
      const int m = kq * 16;
      xsW[(kq * 4 + 0) * 64 + (nl ^ m)] = px[i].x;
      xsW[(kq * 4 + 1) * 64 + (nl ^ m)] = px[i].y;
      xsW[(kq * 4 + 2) * 64 + (nl ^ m)] = px[i].z;
      xsW[(kq * 4 + 3) * 64 + (nl ^ m)] = px[i].w;
      ((float4*)wsW)[lane + i * 64] = pw[i];
    }
    if (kc < 3) {
      const int kb = (kc + 1) * 16;
#pragma unroll
      for (int i = 0; i < 4; i++) {
        const int gn = blockBase + i * 16 + nrow;
        px[i] = (gn < N)
                    ? *(const float4*)(srcM + (size_t)gn * HID + kb + kq * 4)
                    : make_float4(0.f, 0.f, 0.f, 0.f);
        pw[i] = *(const float4*)(Wsrc + (size_t)(kb + i * 4 + wrow) * HID +
                                 wc4 * 4);
      }
    }
#pragma unroll
    for (int k = 0; k < 16; k++) {
      const int sw = (k & 12) << 2;
      const float4 a0 = *(const float4*)&xsW[k * 64 + ((ng * 8) ^ sw)];
      const float4 a1 = *(const float4*)&xsW[k * 64 + ((ng * 8 + 4) ^ sw)];
      const float4 b0 = *(const float4*)&wsW[k * 64 + cg * 8];
      const float4 b1 = *(const float4*)&wsW[k * 64 + cg * 8 + 4];
      const float av[8] = {a0.x, a0.y, a0.z, a0.w, a1.x, a1.y, a1.z, a1.w};
      const float bv[8] = {b0.x, b0.y, b0.z, b0.w, b1.x, b1.y, b1.z, b1.w};
#pragma unroll
      for (int i = 0; i < 8; i++)
#pragma unroll
        for (int j = 0; j < 8; j++) acc[i][j] += av[i] * bv[j];
    }
  }

  __syncthreads();
  if (wid == 1) {
#pragma unroll
    for (int i = 0; i < 8; i++)
#pragma unroll
      for (int j = 0; j < 8; j++) smem[lane * 65 + i * 8 + j] = acc[i][j];
  }
  __syncthreads();
  if (wid == 0) {
    float bj[8];
#pragma unroll
    for (int j = 0; j < 8; j++) bj[j] = bl[cg * 8 + j];
#pragma unroll
    for (int i = 0; i < 8; i++) {
      const int n = blockBase + ng * 8 + i;
      if (n < N) {
        const float4 h0 = *(const float4*)(h + (size_t)n * HID + cg * 8);
        const float4 h1 = *(const float4*)(h + (size_t)n * HID + cg * 8 + 4);
        float4 o0, o1;
        o0.x = h0.x + acc[i][0] + smem[lane * 65 + i * 8 + 0] + bj[0];
        o0.y = h0.y + acc[i][1] + smem[lane * 65 + i * 8 + 1] + bj[1];
        o0.z = h0.z + acc[i][2] + smem[lane * 65 + i * 8 + 2] + bj[2];
        o0.w = h0.w + acc[i][3] + smem[lane * 65 + i * 8 + 3] + bj[3];
        o1.x = h1.x + acc[i][4] + smem[lane * 65 + i * 8 + 4] + bj[4];
        o1.y = h1.y + acc[i][5] + smem[lane * 65 + i * 8 + 5] + bj[5];
        o1.z = h1.z + acc[i][6] + smem[lane * 65 + i * 8 + 6] + bj[6];
        o1.w = h1.w + acc[i][7] + smem[lane * 65 + i * 8 + 7] + bj[7];
        o0.x = o0.x > 0.f ? o0.x : 0.f;
        o0.y = o0.y > 0.f ? o0.y : 0.f;
        o0.z = o0.z > 0.f ? o0.z : 0.f;
        o0.w = o0.w > 0.f ? o0.w : 0.f;
        o1.x = o1.x > 0.f ? o1.x : 0.f;
        o1.y = o1.y > 0.f ? o1.y : 0.f;
        o1.z = o1.z > 0.f ? o1.z : 0.f;
        o1.w = o1.w > 0.f ? o1.w : 0.f;
        *(float4*)(h + (size_t)n * HID + cg * 8) = o0;
        *(float4*)(h + (size_t)n * HID + cg * 8 + 4) = o1;
      }
    }
  }
}

// ---------------- classifier ----------------
__global__ __launch_bounds__(256) void cls_kernel(
    const float* __restrict__ h, const float* __restrict__ Wc,
    const float* __restrict__ bc, float* __restrict__ out, int N) {
  const int gw = (int)((blockIdx.x * (size_t)blockDim.x + threadIdx.x) >> 6);
  const int lane = threadIdx.x & 63;
  if (gw >= N) return;
  float p = h[(size_t)gw * HID + lane] * Wc[lane];
#pragma unroll
  for (int off = 32; off > 0; off >>= 1) p += __shfl_down(p, off, 64);
  if (lane == 0) out[gw] = 1.0f / (1.0f + expf(-(p + bc[0])));
}

extern "C" void kernel_launch(void* const* d_in, const int* in_sizes, int n_in,
                              void* d_out, int out_size, void* d_ws,
                              size_t ws_size, hipStream_t stream) {
  const float* x = (const float*)d_in[0];
  const int* ei = (const int*)d_in[1];
  const float* W_enc = (const float*)d_in[2];
  const float* b_enc = (const float*)d_in[3];
  const float* Wl = (const float*)d_in[4];
  const float* bl = (const float*)d_in[5];
  const float* Wr = (const float*)d_in[6];
  const float* Wc = (const float*)d_in[7];
  const float* bc = (const float*)d_in[8];
  float* out = (float*)d_out;

  const int N = in_sizes[0] / KIN;
  const int E = in_sizes[1] / 2;
  const int* src = ei;
  const int* dst = ei + E;

  char* ws = (char*)d_ws;
  size_t off = 0;
  auto alloc = [&](size_t bytes) -> void* {
    void* p = ws + off;
    off += (bytes + 255) & ~(size_t)255;
    return p;
  };
  float* h = (float*)alloc((size_t)N * HID * sizeof(float));
  float* agg = (float*)alloc((size_t)N * HID * sizeof(float));
  int* cnt = (int*)alloc((size_t)N * sizeof(int));
  int* row_start = (int*)alloc((size_t)(N + 1) * sizeof(int));
  int* cursor = (int*)alloc((size_t)N * sizeof(int));
  float* inv_deg = (float*)alloc((size_t)N * sizeof(float));
  int* csr_src = (int*)alloc((size_t)E * sizeof(int));
  const int nblk = (N + 1023) / 1024;
  int* block_sums = (int*)alloc((size_t)nblk * sizeof(int));

  hipMemsetAsync(cnt, 0, (size_t)N * sizeof(int), stream);
  hipMemsetAsync(cursor, 0, (size_t)N * sizeof(int), stream);

  enc_kernel<<<(N + 63) / 64, 128, 0, stream>>>(x, W_enc, b_enc, h, N);
  hist_kernel<<<(E + 255) / 256, 256, 0, stream>>>(dst, cnt, E, N);
  scanA_kernel<<<nblk, 1024, 0, stream>>>(cnt, block_sums, N);
  scanB_kernel<<<1, 128, 0, stream>>>(block_sums, row_start, nblk, N);
  scanC_kernel<<<nblk, 1024, 0, stream>>>(cnt, block_sums, row_start, inv_deg,
                                          N);
  scatter_kernel<<<(E + 255) / 256, 256, 0, stream>>>(src, dst, row_start,
                                                      cursor, csr_src, E, N);
  for (int l = 0; l < 3; l++) {
    agg_kernel<<<(N + 3) / 4, 256, 0, stream>>>(h, row_start, csr_src, inv_deg,
                                                agg, N);
    update_kernel<<<(N + 63) / 64, 128, 0, stream>>>(
        h, agg, Wl + (size_t)l * HID * HID, bl + (size_t)l * HID,
        Wr + (size_t)l * HID * HID, N);
  }
  cls_kernel<<<(N + 3) / 4, 256, 0, stream>>>(h, Wc, bc, out, N);
}

// Round 5
// 809.810 us; speedup vs baseline: 1.1168x; 1.1168x over previous
//
#include <hip/hip_runtime.h>
#include <math.h>

#define HID 64
#define KIN 512

typedef __attribute__((ext_vector_type(8))) short short8;    // 8 bf16 (4 VGPR)
typedef __attribute__((ext_vector_type(4))) float floatx4;   // MFMA acc

// RNE fp32 -> bf16 (packed pair)
__device__ inline unsigned bf16pair(float a, float b) {
  unsigned ua = __float_as_uint(a);
  unsigned ub = __float_as_uint(b);
  ua = (ua + 0x7FFFu + ((ua >> 16) & 1u)) >> 16;
  ub = (ub + 0x7FFFu + ((ub >> 16) & 1u)) >> 16;
  return ua | (ub << 16);
}
__device__ inline unsigned short bf16one(float a) {
  unsigned ua = __float_as_uint(a);
  return (unsigned short)((ua + 0x7FFFu + ((ua >> 16) & 1u)) >> 16);
}

// ---------- one-time: Wt[c][k] = bf16(W_enc[k][c]), 64x512 ----------
__global__ __launch_bounds__(256) void wt_kernel(const float* __restrict__ W,
                                                 unsigned short* __restrict__ wt) {
  const int t = blockIdx.x * 256 + threadIdx.x;  // 0..32767
  if (t < 64 * KIN) {
    const int c = t >> 9;
    const int k = t & 511;
    wt[c * KIN + k] = bf16one(W[k * HID + c]);
  }
}

// ---------- encoder: h = x @ W_enc + b_enc via bf16 MFMA ----------
// block 256 thr (4 waves), tile 64 nodes x 64 cols, K-chunks of 32,
// double-buffered LDS of 16B fragment units with XOR swizzle
// u = idx*4 + (q ^ ((idx>>1)&3))  -> all fragment reads <=2-way (free).
// Wave w owns rows w*16..+16; 4 col-tiles => 4 acc frags.
__global__ __launch_bounds__(256) void enc_kernel(
    const float* __restrict__ x, const unsigned short* __restrict__ wt,
    const float* __restrict__ b, float* __restrict__ h, int N) {
  __shared__ uint4 sx[2][256];  // 8 KB  x-tile bf16 fragments
  __shared__ uint4 sw[2][256];  // 8 KB  W-tile bf16 fragments
  const int t = threadIdx.x;
  const int lane = t & 63;
  const int wid = t >> 6;
  const int m15 = lane & 15;
  const int quad = lane >> 4;
  const int blockBase = blockIdx.x * 64;

  // staging indices: thread t stages 8 consecutive k of row/col (t>>2)
  const int rs = t >> 2;        // 0..63 (node row AND W col)
  const int qs = t & 3;         // which 8-k group in the 32-k chunk
  const int us = rs * 4 + (qs ^ ((rs >> 1) & 3));
  const int gn = blockBase + rs;
  const bool valid = gn < N;
  const float* xp = x + (size_t)(valid ? gn : 0) * KIN + qs * 8;
  const unsigned short* wp = wt + (size_t)rs * KIN + qs * 8;

  // fragment read units
  const int arow = wid * 16 + m15;
  const int ua = arow * 4 + (quad ^ ((arow >> 1) & 3));
  int ub[4];
#pragma unroll
  for (int c4 = 0; c4 < 4; c4++) {
    const int col = c4 * 16 + m15;
    ub[c4] = col * 4 + (quad ^ ((col >> 1) & 3));
  }

  floatx4 acc[4];
#pragma unroll
  for (int c4 = 0; c4 < 4; c4++)
#pragma unroll
    for (int j = 0; j < 4; j++) acc[c4][j] = 0.f;

  float4 fx0, fx1;
  uint4 wv;
  // prefetch chunk 0
  if (valid) {
    fx0 = *(const float4*)(xp);
    fx1 = *(const float4*)(xp + 4);
  } else {
    fx0 = fx1 = make_float4(0.f, 0.f, 0.f, 0.f);
  }
  wv = *(const uint4*)(wp);

  for (int kc = 0; kc < 16; kc++) {
    const int cur = kc & 1;
    uint4 xu;
    xu.x = bf16pair(fx0.x, fx0.y);
    xu.y = bf16pair(fx0.z, fx0.w);
    xu.z = bf16pair(fx1.x, fx1.y);
    xu.w = bf16pair(fx1.z, fx1.w);
    sx[cur][us] = xu;
    sw[cur][us] = wv;
    __syncthreads();
    if (kc < 15) {  // issue next chunk's global loads (overlap w/ MFMA)
      const int ko = (kc + 1) * 32;
      if (valid) {
        fx0 = *(const float4*)(xp + ko);
        fx1 = *(const float4*)(xp + ko + 4);
      }
      wv = *(const uint4*)(wp + ko);
    }
    const short8 a = __builtin_bit_cast(short8, sx[cur][ua]);
#pragma unroll
    for (int c4 = 0; c4 < 4; c4++) {
      const short8 bf = __builtin_bit_cast(short8, sw[cur][ub[c4]]);
      acc[c4] = __builtin_amdgcn_mfma_f32_16x16x32_bf16(a, bf, acc[c4], 0, 0, 0);
    }
  }

  // epilogue: C/D layout col=lane&15, row=quad*4+reg
#pragma unroll
  for (int c4 = 0; c4 < 4; c4++) {
    const float bias = b[c4 * 16 + m15];
#pragma unroll
    for (int r = 0; r < 4; r++) {
      const int row = blockBase + wid * 16 + quad * 4 + r;
      if (row < N) h[(size_t)row * HID + c4 * 16 + m15] = acc[c4][r] + bias;
    }
  }
}

// ---------------- degree histogram ----------------
__global__ void hist_kernel(const int* __restrict__ dst, int* __restrict__ cnt,
                            int E, int N) {
  int e = blockIdx.x * blockDim.x + threadIdx.x;
  if (e < E) {
    int d = dst[e];
    if ((unsigned)d < (unsigned)N) atomicAdd(&cnt[d], 1);
  }
}

// ---------------- parallel scan: phase A (block sums) ----------------
__global__ __launch_bounds__(1024) void scanA_kernel(
    const int* __restrict__ cnt, int* __restrict__ block_sums, int N) {
  __shared__ int red[1024];
  const int tid = threadIdx.x;
  const int i = blockIdx.x * 1024 + tid;
  red[tid] = (i < N) ? cnt[i] : 0;
  __syncthreads();
  for (int off = 512; off > 0; off >>= 1) {
    if (tid < off) red[tid] += red[tid + off];
    __syncthreads();
  }
  if (tid == 0) block_sums[blockIdx.x] = red[0];
}

// ---------------- phase B: scan block sums (single block) ----------------
__global__ __launch_bounds__(128) void scanB_kernel(
    int* __restrict__ block_sums, int* __restrict__ row_start, int nblk,
    int N) {
  __shared__ int part[128];
  const int tid = threadIdx.x;
  part[tid] = (tid < nblk) ? block_sums[tid] : 0;
  __syncthreads();
  for (int off = 1; off < 128; off <<= 1) {
    int t = (tid >= off) ? part[tid - off] : 0;
    __syncthreads();
    part[tid] += t;
    __syncthreads();
  }
  if (tid < nblk) block_sums[tid] = (tid > 0) ? part[tid - 1] : 0;  // exclusive
  if (tid == 127) row_start[N] = part[127];
}

// ---------------- phase C: local scan + apply offset ----------------
__global__ __launch_bounds__(1024) void scanC_kernel(
    const int* __restrict__ cnt, const int* __restrict__ block_sums,
    int* __restrict__ row_start, float* __restrict__ inv_deg, int N) {
  __shared__ int part[1024];
  const int tid = threadIdx.x;
  const int i = blockIdx.x * 1024 + tid;
  const int v = (i < N) ? cnt[i] : 0;
  part[tid] = v;
  __syncthreads();
  for (int off = 1; off < 1024; off <<= 1) {
    int t = (tid >= off) ? part[tid - off] : 0;
    __syncthreads();
    part[tid] += t;
    __syncthreads();
  }
  if (i < N) {
    row_start[i] = block_sums[blockIdx.x] + part[tid] - v;  // exclusive
    inv_deg[i] = (v > 0) ? 1.0f / (float)v : 0.0f;
  }
}

// ---------------- bucket edges by dst (CSR) ----------------
__global__ void scatter_kernel(const int* __restrict__ src,
                               const int* __restrict__ dst,
                               const int* __restrict__ row_start,
                               int* __restrict__ cursor,
                               int* __restrict__ csr_src, int E, int N) {
  int e = blockIdx.x * blockDim.x + threadIdx.x;
  if (e < E) {
    int d = dst[e];
    if ((unsigned)d < (unsigned)N) {
      int pos = row_start[d] + atomicAdd(&cursor[d], 1);
      int s = src[e];
      if ((unsigned)s >= (unsigned)N) s = 0;
      csr_src[pos] = s;
    }
  }
}

// ---------------- mean aggregation ----------------
// one wave per node; lane = (edge-subgroup 0..3, float4-idx 0..15).
__global__ __launch_bounds__(256) void agg_kernel(
    const float* __restrict__ h, const int* __restrict__ row_start,
    const int* __restrict__ csr_src, const float* __restrict__ inv_deg,
    float* __restrict__ agg, int N) {
  const int gw = (int)((blockIdx.x * (size_t)blockDim.x + threadIdx.x) >> 6);
  const int lane = threadIdx.x & 63;
  if (gw >= N) return;
  const int sub = lane >> 4;
  const int fq = lane & 15;
  const int s = row_start[gw];
  const int e = row_start[gw + 1];
  float4 acc = make_float4(0.f, 0.f, 0.f, 0.f);
  for (int i = s; i < e; i += 4) {
    const int ei = i + sub;
    if (ei < e) {
      const int n = csr_src[ei];
      const float4 v = *(const float4*)(h + (size_t)n * HID + fq * 4);
      acc.x += v.x;
      acc.y += v.y;
      acc.z += v.z;
      acc.w += v.w;
    }
  }
#pragma unroll
  for (int off = 32; off >= 16; off >>= 1) {
    acc.x += __shfl_down(acc.x, off, 64);
    acc.y += __shfl_down(acc.y, off, 64);
    acc.z += __shfl_down(acc.z, off, 64);
    acc.w += __shfl_down(acc.w, off, 64);
  }
  if (sub == 0) {
    const float id = inv_deg[gw];
    float4 o;
    o.x = acc.x * id;
    o.y = acc.y * id;
    o.z = acc.z * id;
    o.w = acc.w * id;
    *(float4*)(agg + (size_t)gw * HID + fq * 4) = o;
  }
}

// -------- layer update: h = relu(h + agg@Wl + bl + h@Wr) -------- (R3 form)
__global__ __launch_bounds__(128) void update_kernel(
    float* __restrict__ h, const float* __restrict__ agg,
    const float* __restrict__ Wl, const float* __restrict__ bl,
    const float* __restrict__ Wr, int N) {
  __shared__ float xs[32 * 132];
  __shared__ float ws[32 * 64];
  const int tid = threadIdx.x;
  const int lane = tid & 63;
  const int wid = tid >> 6;
  const int ng = lane >> 3;
  const int cg = lane & 7;
  const int blockBase = blockIdx.x * 128;

  float acc[8][8];
#pragma unroll
  for (int i = 0; i < 8; i++)
#pragma unroll
    for (int j = 0; j < 8; j++) acc[i][j] = 0.f;

  for (int ph = 0; ph < 4; ph++) {
    const float* __restrict__ src = (ph < 2) ? agg : h;
    const float* __restrict__ Wsrc = (ph < 2) ? Wl : Wr;
    const int ko = (ph & 1) * 32;
#pragma unroll
    for (int i = 0; i < 8; i++) {
      const int v = tid + i * 128;
      const int nl = v >> 3;
      const int kq = v & 7;
      const int gn = blockBase + nl;
      float4 xv = make_float4(0.f, 0.f, 0.f, 0.f);
      if (gn < N)
        xv = *(const float4*)(src + (size_t)gn * HID + ko + kq * 4);
      xs[(kq * 4 + 0) * 132 + nl] = xv.x;
      xs[(kq * 4 + 1) * 132 + nl] = xv.y;
      xs[(kq * 4 + 2) * 132 + nl] = xv.z;
      xs[(kq * 4 + 3) * 132 + nl] = xv.w;
    }
    {
      const float4* Wg = (const float4*)(Wsrc + (size_t)ko * HID);
      float4* wsv = (float4*)ws;
#pragma unroll
      for (int i = 0; i < 4; i++) wsv[tid + i * 128] = Wg[tid + i * 128];
    }
    __syncthreads();

    const int nb = wid * 64 + ng * 8;
#pragma unroll 4
    for (int k = 0; k < 32; k++) {
      const float4 a0 = *(const float4*)&xs[k * 132 + nb];
      const float4 a1 = *(const float4*)&xs[k * 132 + nb + 4];
      const float4 b0 = *(const float4*)&ws[k * HID + cg * 8];
      const float4 b1 = *(const float4*)&ws[k * HID + cg * 8 + 4];
      const float av[8] = {a0.x, a0.y, a0.z, a0.w, a1.x, a1.y, a1.z, a1.w};
      const float bv[8] = {b0.x, b0.y, b0.z, b0.w, b1.x, b1.y, b1.z, b1.w};
#pragma unroll
      for (int i = 0; i < 8; i++)
#pragma unroll
        for (int j = 0; j < 8; j++) acc[i][j] += av[i] * bv[j];
    }
    __syncthreads();
  }

  float bj[8];
#pragma unroll
  for (int j = 0; j < 8; j++) bj[j] = bl[cg * 8 + j];
  const int nb2 = blockBase + wid * 64 + ng * 8;
#pragma unroll
  for (int i = 0; i < 8; i++) {
    const int n = nb2 + i;
    if (n < N) {
      const float4 h0 = *(const float4*)(h + (size_t)n * HID + cg * 8);
      const float4 h1 = *(const float4*)(h + (size_t)n * HID + cg * 8 + 4);
      float4 o0, o1;
      o0.x = h0.x + acc[i][0] + bj[0];
      o0.y = h0.y + acc[i][1] + bj[1];
      o0.z = h0.z + acc[i][2] + bj[2];
      o0.w = h0.w + acc[i][3] + bj[3];
      o1.x = h1.x + acc[i][4] + bj[4];
      o1.y = h1.y + acc[i][5] + bj[5];
      o1.z = h1.z + acc[i][6] + bj[6];
      o1.w = h1.w + acc[i][7] + bj[7];
      o0.x = o0.x > 0.f ? o0.x : 0.f;
      o0.y = o0.y > 0.f ? o0.y : 0.f;
      o0.z = o0.z > 0.f ? o0.z : 0.f;
      o0.w = o0.w > 0.f ? o0.w : 0.f;
      o1.x = o1.x > 0.f ? o1.x : 0.f;
      o1.y = o1.y > 0.f ? o1.y : 0.f;
      o1.z = o1.z > 0.f ? o1.z : 0.f;
      o1.w = o1.w > 0.f ? o1.w : 0.f;
      *(float4*)(h + (size_t)n * HID + cg * 8) = o0;
      *(float4*)(h + (size_t)n * HID + cg * 8 + 4) = o1;
    }
  }
}

// ---------------- classifier ----------------
__global__ __launch_bounds__(256) void cls_kernel(
    const float* __restrict__ h, const float* __restrict__ Wc,
    const float* __restrict__ bc, float* __restrict__ out, int N) {
  const int gw = (int)((blockIdx.x * (size_t)blockDim.x + threadIdx.x) >> 6);
  const int lane = threadIdx.x & 63;
  if (gw >= N) return;
  float p = h[(size_t)gw * HID + lane] * Wc[lane];
#pragma unroll
  for (int off = 32; off > 0; off >>= 1) p += __shfl_down(p, off, 64);
  if (lane == 0) out[gw] = 1.0f / (1.0f + expf(-(p + bc[0])));
}

extern "C" void kernel_launch(void* const* d_in, const int* in_sizes, int n_in,
                              void* d_out, int out_size, void* d_ws,
                              size_t ws_size, hipStream_t stream) {
  const float* x = (const float*)d_in[0];
  const int* ei = (const int*)d_in[1];
  const float* W_enc = (const float*)d_in[2];
  const float* b_enc = (const float*)d_in[3];
  const float* Wl = (const float*)d_in[4];
  const float* bl = (const float*)d_in[5];
  const float* Wr = (const float*)d_in[6];
  const float* Wc = (const float*)d_in[7];
  const float* bc = (const float*)d_in[8];
  float* out = (float*)d_out;

  const int N = in_sizes[0] / KIN;
  const int E = in_sizes[1] / 2;
  const int* src = ei;
  const int* dst = ei + E;

  char* ws = (char*)d_ws;
  size_t off = 0;
  auto alloc = [&](size_t bytes) -> void* {
    void* p = ws + off;
    off += (bytes + 255) & ~(size_t)255;
    return p;
  };
  float* h = (float*)alloc((size_t)N * HID * sizeof(float));
  float* agg = (float*)alloc((size_t)N * HID * sizeof(float));
  int* cnt = (int*)alloc((size_t)N * sizeof(int));
  int* row_start = (int*)alloc((size_t)(N + 1) * sizeof(int));
  int* cursor = (int*)alloc((size_t)N * sizeof(int));
  float* inv_deg = (float*)alloc((size_t)N * sizeof(float));
  int* csr_src = (int*)alloc((size_t)E * sizeof(int));
  const int nblk = (N + 1023) / 1024;
  int* block_sums = (int*)alloc((size_t)nblk * sizeof(int));
  unsigned short* wt = (unsigned short*)alloc((size_t)HID * KIN * sizeof(unsigned short));

  hipMemsetAsync(cnt, 0, (size_t)N * sizeof(int), stream);
  hipMemsetAsync(cursor, 0, (size_t)N * sizeof(int), stream);

  wt_kernel<<<(HID * KIN + 255) / 256, 256, 0, stream>>>(W_enc, wt);
  enc_kernel<<<(N + 63) / 64, 256, 0, stream>>>(x, wt, b_enc, h, N);
  hist_kernel<<<(E + 255) / 256, 256, 0, stream>>>(dst, cnt, E, N);
  scanA_kernel<<<nblk, 1024, 0, stream>>>(cnt, block_sums, N);
  scanB_kernel<<<1, 128, 0, stream>>>(block_sums, row_start, nblk, N);
  scanC_kernel<<<nblk, 1024, 0, stream>>>(cnt, block_sums, row_start, inv_deg,
                                          N);
  scatter_kernel<<<(E + 255) / 256, 256, 0, stream>>>(src, dst, row_start,
                                                      cursor, csr_src, E, N);
  for (int l = 0; l < 3; l++) {
    agg_kernel<<<(N + 3) / 4, 256, 0, stream>>>(h, row_start, csr_src, inv_deg,
                                                agg, N);
    update_kernel<<<(N + 127) / 128, 128, 0, stream>>>(
        h, agg, Wl + (size_t)l * HID * HID, bl + (size_t)l * HID,
        Wr + (size_t)l * HID * HID, N);
  }
  cls_kernel<<<(N + 3) / 4, 256, 0, stream>>>(h, Wc, bc, out, N);
}

// Round 6
// 798.771 us; speedup vs baseline: 1.1322x; 1.0138x over previous
//
#include <hip/hip_runtime.h>
#include <math.h>

#define HID 64
#define KIN 512

typedef __attribute__((ext_vector_type(8))) short short8;   // 8 bf16 (4 VGPR)
typedef __attribute__((ext_vector_type(4))) float floatx4;  // MFMA acc

// RNE fp32 -> bf16
__device__ inline unsigned bf16pair(float a, float b) {
  unsigned ua = __float_as_uint(a);
  unsigned ub = __float_as_uint(b);
  ua = (ua + 0x7FFFu + ((ua >> 16) & 1u)) >> 16;
  ub = (ub + 0x7FFFu + ((ub >> 16) & 1u)) >> 16;
  return ua | (ub << 16);
}
__device__ inline unsigned short bf16one(float a) {
  unsigned ua = __float_as_uint(a);
  return (unsigned short)((ua + 0x7FFFu + ((ua >> 16) & 1u)) >> 16);
}
__device__ inline float bflo(unsigned u) { return __uint_as_float(u << 16); }
__device__ inline float bfhi(unsigned u) {
  return __uint_as_float(u & 0xffff0000u);
}

// ---- one-time weight prep: transpose + bf16 ----
// blocks 0..127: wte[c][k] = bf16(W_enc[k][c])  (64 x 512)
// blocks 128..223: wlrt[mat][c][k] = bf16(W[k][c]), mats = Wl0..2, Wr0..2
__global__ __launch_bounds__(256) void prep_kernel(
    const float* __restrict__ We, const float* __restrict__ Wl,
    const float* __restrict__ Wr, unsigned short* __restrict__ wte,
    unsigned short* __restrict__ wlrt) {
  const int blk = blockIdx.x;
  const int tid = threadIdx.x;
  if (blk < 128) {
    const int t = blk * 256 + tid;
    const int c = t >> 9, k = t & 511;
    wte[c * KIN + k] = bf16one(We[k * HID + c]);
  } else {
    const int t = (blk - 128) * 256 + tid;  // 0..24575
    const int mat = t >> 12;                // 0..5
    const int e = t & 4095;
    const int c = e >> 6, k = e & 63;
    const float* src =
        (mat < 3) ? (Wl + (size_t)mat * 4096) : (Wr + (size_t)(mat - 3) * 4096);
    wlrt[(size_t)mat * 4096 + c * 64 + k] = bf16one(src[k * 64 + c]);
  }
}

// ---- encoder: hb = bf16(x @ W_enc + b_enc) via MFMA (R5 structure) ----
__global__ __launch_bounds__(256) void enc_kernel(
    const float* __restrict__ x, const unsigned short* __restrict__ wt,
    const float* __restrict__ b, unsigned short* __restrict__ hb, int N) {
  __shared__ uint4 sx[2][256];
  __shared__ uint4 sw[2][256];
  const int t = threadIdx.x;
  const int lane = t & 63;
  const int wid = t >> 6;
  const int m15 = lane & 15;
  const int quad = lane >> 4;
  const int blockBase = blockIdx.x * 64;

  const int rs = t >> 2;
  const int qs = t & 3;
  const int us = rs * 4 + (qs ^ ((rs >> 1) & 3));
  const int gn = blockBase + rs;
  const bool valid = gn < N;
  const float* xp = x + (size_t)(valid ? gn : 0) * KIN + qs * 8;
  const unsigned short* wp = wt + (size_t)rs * KIN + qs * 8;

  const int arow = wid * 16 + m15;
  const int ua = arow * 4 + (quad ^ ((arow >> 1) & 3));
  int ub[4];
#pragma unroll
  for (int c4 = 0; c4 < 4; c4++) {
    const int col = c4 * 16 + m15;
    ub[c4] = col * 4 + (quad ^ ((col >> 1) & 3));
  }

  floatx4 acc[4];
#pragma unroll
  for (int c4 = 0; c4 < 4; c4++)
#pragma unroll
    for (int j = 0; j < 4; j++) acc[c4][j] = 0.f;

  float4 fx0, fx1;
  uint4 wv;
  if (valid) {
    fx0 = *(const float4*)(xp);
    fx1 = *(const float4*)(xp + 4);
  } else {
    fx0 = fx1 = make_float4(0.f, 0.f, 0.f, 0.f);
  }
  wv = *(const uint4*)(wp);

  for (int kc = 0; kc < 16; kc++) {
    const int cur = kc & 1;
    uint4 xu;
    xu.x = bf16pair(fx0.x, fx0.y);
    xu.y = bf16pair(fx0.z, fx0.w);
    xu.z = bf16pair(fx1.x, fx1.y);
    xu.w = bf16pair(fx1.z, fx1.w);
    sx[cur][us] = xu;
    sw[cur][us] = wv;
    __syncthreads();
    if (kc < 15) {
      const int ko = (kc + 1) * 32;
      if (valid) {
        fx0 = *(const float4*)(xp + ko);
        fx1 = *(const float4*)(xp + ko + 4);
      }
      wv = *(const uint4*)(wp + ko);
    }
    const short8 a = __builtin_bit_cast(short8, sx[cur][ua]);
#pragma unroll
    for (int c4 = 0; c4 < 4; c4++) {
      const short8 bf = __builtin_bit_cast(short8, sw[cur][ub[c4]]);
      acc[c4] =
          __builtin_amdgcn_mfma_f32_16x16x32_bf16(a, bf, acc[c4], 0, 0, 0);
    }
  }

#pragma unroll
  for (int c4 = 0; c4 < 4; c4++) {
    const float bias = b[c4 * 16 + m15];
#pragma unroll
    for (int r = 0; r < 4; r++) {
      const int row = blockBase + wid * 16 + quad * 4 + r;
      if (row < N)
        hb[(size_t)row * HID + c4 * 16 + m15] = bf16one(acc[c4][r] + bias);
    }
  }
}

// ---------------- degree histogram ----------------
__global__ void hist_kernel(const int* __restrict__ dst, int* __restrict__ cnt,
                            int E, int N) {
  int e = blockIdx.x * blockDim.x + threadIdx.x;
  if (e < E) {
    int d = dst[e];
    if ((unsigned)d < (unsigned)N) atomicAdd(&cnt[d], 1);
  }
}

// ---------------- parallel scan ----------------
__global__ __launch_bounds__(1024) void scanA_kernel(
    const int* __restrict__ cnt, int* __restrict__ block_sums, int N) {
  __shared__ int red[1024];
  const int tid = threadIdx.x;
  const int i = blockIdx.x * 1024 + tid;
  red[tid] = (i < N) ? cnt[i] : 0;
  __syncthreads();
  for (int off = 512; off > 0; off >>= 1) {
    if (tid < off) red[tid] += red[tid + off];
    __syncthreads();
  }
  if (tid == 0) block_sums[blockIdx.x] = red[0];
}

__global__ __launch_bounds__(128) void scanB_kernel(
    int* __restrict__ block_sums, int* __restrict__ row_start, int nblk,
    int N) {
  __shared__ int part[128];
  const int tid = threadIdx.x;
  part[tid] = (tid < nblk) ? block_sums[tid] : 0;
  __syncthreads();
  for (int off = 1; off < 128; off <<= 1) {
    int t = (tid >= off) ? part[tid - off] : 0;
    __syncthreads();
    part[tid] += t;
    __syncthreads();
  }
  if (tid < nblk) block_sums[tid] = (tid > 0) ? part[tid - 1] : 0;
  if (tid == 127) row_start[N] = part[127];
}

__global__ __launch_bounds__(1024) void scanC_kernel(
    const int* __restrict__ cnt, const int* __restrict__ block_sums,
    int* __restrict__ row_start, float* __restrict__ inv_deg, int N) {
  __shared__ int part[1024];
  const int tid = threadIdx.x;
  const int i = blockIdx.x * 1024 + tid;
  const int v = (i < N) ? cnt[i] : 0;
  part[tid] = v;
  __syncthreads();
  for (int off = 1; off < 1024; off <<= 1) {
    int t = (tid >= off) ? part[tid - off] : 0;
    __syncthreads();
    part[tid] += t;
    __syncthreads();
  }
  if (i < N) {
    row_start[i] = block_sums[blockIdx.x] + part[tid] - v;
    inv_deg[i] = (v > 0) ? 1.0f / (float)v : 0.0f;
  }
}

// ---------------- bucket edges by dst (CSR) ----------------
__global__ void scatter_kernel(const int* __restrict__ src,
                               const int* __restrict__ dst,
                               const int* __restrict__ row_start,
                               int* __restrict__ cursor,
                               int* __restrict__ csr_src, int E, int N) {
  int e = blockIdx.x * blockDim.x + threadIdx.x;
  if (e < E) {
    int d = dst[e];
    if ((unsigned)d < (unsigned)N) {
      int pos = row_start[d] + atomicAdd(&cursor[d], 1);
      int s = src[e];
      if ((unsigned)s >= (unsigned)N) s = 0;
      csr_src[pos] = s;
    }
  }
}

// ===== fused layer: gather-mean -> [agg|h]@[Wl;Wr] MFMA -> residual/relu
//       -> bf16 store (+ optional classifier on last layer) =====
// block = 256 thr (4 waves) = 64 nodes. LDS bf16 tiles in 16B units with
// swizzle u = row*8 + (g ^ (row&7)) -> all b128 accesses at wave64 floor.
__global__ __launch_bounds__(256) void layer_kernel(
    const unsigned short* __restrict__ hin, unsigned short* __restrict__ hout,
    const int* __restrict__ row_start, const int* __restrict__ csr_src,
    const float* __restrict__ inv_deg, const unsigned short* __restrict__ Wlt,
    const unsigned short* __restrict__ Wrt, const float* __restrict__ bl,
    const float* __restrict__ Wc, const float* __restrict__ bc,
    float* __restrict__ out, int N) {
  __shared__ uint4 sAgg[512];  // 8 KB agg tile
  __shared__ uint4 sH[512];    // 8 KB own h rows
  __shared__ uint4 sWl[512];   // 8 KB Wl (col-major bf16)
  __shared__ uint4 sWr[512];   // 8 KB Wr
  const int tid = threadIdx.x;
  const int lane = tid & 63;
  const int wid = tid >> 6;
  const int m15 = lane & 15;
  const int quad = lane >> 4;
  const int blockBase = blockIdx.x * 64;

  // ---- stage own h rows + both weight mats ----
  {
    const int r = tid >> 2;
    const int gp = tid & 3;
    const int g0 = gp * 2, g1 = gp * 2 + 1;
    const int u0 = r * 8 + (g0 ^ (r & 7));
    const int u1 = r * 8 + (g1 ^ (r & 7));
    const int gn = blockBase + r;
    if (gn < N) {
      const uint4* hp = (const uint4*)(hin + (size_t)gn * HID);
      sH[u0] = hp[g0];
      sH[u1] = hp[g1];
    } else {
      const uint4 z = make_uint4(0, 0, 0, 0);
      sH[u0] = z;
      sH[u1] = z;
    }
    const uint4* wl = (const uint4*)(Wlt + (size_t)r * HID);
    const uint4* wr = (const uint4*)(Wrt + (size_t)r * HID);
    sWl[u0] = wl[g0];
    sWl[u1] = wl[g1];
    sWr[u0] = wr[g0];
    sWr[u1] = wr[g1];
  }

  // ---- mean-aggregate neighbors into sAgg (wave per 16 nodes) ----
  {
    const int sub = quad;   // 0..3: edge subgroup
    const int fq = m15;     // uint2 (4 bf16) column group
    for (int i = 0; i < 16; i++) {
      const int nl = wid * 16 + i;
      const int gn = blockBase + nl;
      float4 a = make_float4(0.f, 0.f, 0.f, 0.f);
      float id = 0.f;
      if (gn < N) {
        id = inv_deg[gn];
        const int s = row_start[gn];
        const int e = row_start[gn + 1];
        for (int j = s + sub; j < e; j += 4) {
          const int nb = csr_src[j];
          const uint2 v = *(const uint2*)(hin + (size_t)nb * HID + fq * 4);
          a.x += bflo(v.x);
          a.y += bfhi(v.x);
          a.z += bflo(v.y);
          a.w += bfhi(v.y);
        }
      }
      a.x += __shfl_down(a.x, 32, 64);
      a.y += __shfl_down(a.y, 32, 64);
      a.z += __shfl_down(a.z, 32, 64);
      a.w += __shfl_down(a.w, 32, 64);
      a.x += __shfl_down(a.x, 16, 64);
      a.y += __shfl_down(a.y, 16, 64);
      a.z += __shfl_down(a.z, 16, 64);
      a.w += __shfl_down(a.w, 16, 64);
      if (sub == 0) {
        uint2 p;
        p.x = bf16pair(a.x * id, a.y * id);
        p.y = bf16pair(a.z * id, a.w * id);
        const int g = fq >> 1;
        uint2* dst = (uint2*)&sAgg[nl * 8 + (g ^ (nl & 7))];
        dst[fq & 1] = p;
      }
    }
  }
  __syncthreads();

  // ---- MFMA: acc = agg@Wl + h@Wr ----
  floatx4 acc[4];
#pragma unroll
  for (int c4 = 0; c4 < 4; c4++)
#pragma unroll
    for (int j = 0; j < 4; j++) acc[c4][j] = 0.f;

  const int arow = wid * 16 + m15;
#pragma unroll
  for (int c = 0; c < 2; c++) {
    const int ua = arow * 8 + ((c * 4 + quad) ^ (arow & 7));
    const short8 aA = __builtin_bit_cast(short8, sAgg[ua]);
    const short8 aH = __builtin_bit_cast(short8, sH[ua]);
#pragma unroll
    for (int c4 = 0; c4 < 4; c4++) {
      const int col = c4 * 16 + m15;
      const int ub = col * 8 + ((c * 4 + quad) ^ (col & 7));
      acc[c4] = __builtin_amdgcn_mfma_f32_16x16x32_bf16(
          aA, __builtin_bit_cast(short8, sWl[ub]), acc[c4], 0, 0, 0);
      acc[c4] = __builtin_amdgcn_mfma_f32_16x16x32_bf16(
          aH, __builtin_bit_cast(short8, sWr[ub]), acc[c4], 0, 0, 0);
    }
  }

  // ---- epilogue: residual + bias + relu; bf16 store; optional cls ----
  float vals[4][4];
#pragma unroll
  for (int c4 = 0; c4 < 4; c4++) {
    const float bias = bl[c4 * 16 + m15];
#pragma unroll
    for (int r = 0; r < 4; r++) {
      const int rowl = wid * 16 + quad * 4 + r;
      const unsigned short hv =
          ((const unsigned short*)
               sH)[(rowl * 8 + ((c4 * 2 + (m15 >> 3)) ^ (rowl & 7))) * 8 +
                   (m15 & 7)];
      const float v = __uint_as_float((unsigned)hv << 16) + acc[c4][r] + bias;
      vals[c4][r] = v > 0.f ? v : 0.f;
    }
  }
#pragma unroll
  for (int c4 = 0; c4 < 4; c4++) {
#pragma unroll
    for (int r = 0; r < 4; r++) {
      const int rowg = blockBase + wid * 16 + quad * 4 + r;
      if (rowg < N)
        hout[(size_t)rowg * HID + c4 * 16 + m15] = bf16one(vals[c4][r]);
    }
  }
  if (Wc != nullptr) {
    float p[4] = {0.f, 0.f, 0.f, 0.f};
#pragma unroll
    for (int c4 = 0; c4 < 4; c4++) {
      const float wc = Wc[c4 * 16 + m15];
#pragma unroll
      for (int r = 0; r < 4; r++) p[r] += vals[c4][r] * wc;
    }
#pragma unroll
    for (int off = 1; off < 16; off <<= 1) {
#pragma unroll
      for (int r = 0; r < 4; r++) p[r] += __shfl_xor(p[r], off, 16);
    }
    if (m15 == 0) {
      const float bb = bc[0];
#pragma unroll
      for (int r = 0; r < 4; r++) {
        const int rowg = blockBase + wid * 16 + quad * 4 + r;
        if (rowg < N) out[rowg] = 1.0f / (1.0f + expf(-(p[r] + bb)));
      }
    }
  }
}

extern "C" void kernel_launch(void* const* d_in, const int* in_sizes, int n_in,
                              void* d_out, int out_size, void* d_ws,
                              size_t ws_size, hipStream_t stream) {
  const float* x = (const float*)d_in[0];
  const int* ei = (const int*)d_in[1];
  const float* W_enc = (const float*)d_in[2];
  const float* b_enc = (const float*)d_in[3];
  const float* Wl = (const float*)d_in[4];
  const float* bl = (const float*)d_in[5];
  const float* Wr = (const float*)d_in[6];
  const float* Wc = (const float*)d_in[7];
  const float* bc = (const float*)d_in[8];
  float* out = (float*)d_out;

  const int N = in_sizes[0] / KIN;
  const int E = in_sizes[1] / 2;
  const int* src = ei;
  const int* dst = ei + E;

  char* ws = (char*)d_ws;
  size_t off = 0;
  auto alloc = [&](size_t bytes) -> void* {
    void* p = ws + off;
    off += (bytes + 255) & ~(size_t)255;
    return p;
  };
  unsigned short* hb0 =
      (unsigned short*)alloc((size_t)N * HID * sizeof(unsigned short));
  unsigned short* hb1 =
      (unsigned short*)alloc((size_t)N * HID * sizeof(unsigned short));
  int* cnt = (int*)alloc((size_t)N * sizeof(int));
  int* row_start = (int*)alloc((size_t)(N + 1) * sizeof(int));
  int* cursor = (int*)alloc((size_t)N * sizeof(int));
  float* inv_deg = (float*)alloc((size_t)N * sizeof(float));
  int* csr_src = (int*)alloc((size_t)E * sizeof(int));
  const int nblk = (N + 1023) / 1024;
  int* block_sums = (int*)alloc((size_t)nblk * sizeof(int));
  unsigned short* wte =
      (unsigned short*)alloc((size_t)HID * KIN * sizeof(unsigned short));
  unsigned short* wlrt =
      (unsigned short*)alloc((size_t)6 * HID * HID * sizeof(unsigned short));

  hipMemsetAsync(cnt, 0, (size_t)N * sizeof(int), stream);
  hipMemsetAsync(cursor, 0, (size_t)N * sizeof(int), stream);

  prep_kernel<<<224, 256, 0, stream>>>(W_enc, Wl, Wr, wte, wlrt);
  hist_kernel<<<(E + 255) / 256, 256, 0, stream>>>(dst, cnt, E, N);
  scanA_kernel<<<nblk, 1024, 0, stream>>>(cnt, block_sums, N);
  scanB_kernel<<<1, 128, 0, stream>>>(block_sums, row_start, nblk, N);
  scanC_kernel<<<nblk, 1024, 0, stream>>>(cnt, block_sums, row_start, inv_deg,
                                          N);
  scatter_kernel<<<(E + 255) / 256, 256, 0, stream>>>(src, dst, row_start,
                                                      cursor, csr_src, E, N);
  enc_kernel<<<(N + 63) / 64, 256, 0, stream>>>(x, wte, b_enc, hb0, N);

  const int nb64 = (N + 63) / 64;
  // layer 0: hb0 -> hb1
  layer_kernel<<<nb64, 256, 0, stream>>>(hb0, hb1, row_start, csr_src, inv_deg,
                                         wlrt, wlrt + 3 * 4096, bl, nullptr,
                                         nullptr, nullptr, N);
  // layer 1: hb1 -> hb0
  layer_kernel<<<nb64, 256, 0, stream>>>(hb1, hb0, row_start, csr_src, inv_deg,
                                         wlrt + 4096, wlrt + 4 * 4096, bl + 64,
                                         nullptr, nullptr, nullptr, N);
  // layer 2: hb0 -> hb1, fused classifier
  layer_kernel<<<nb64, 256, 0, stream>>>(hb0, hb1, row_start, csr_src, inv_deg,
                                         wlrt + 2 * 4096, wlrt + 5 * 4096,
                                         bl + 128, Wc, bc, out, N);
}

// Round 7
// 593.893 us; speedup vs baseline: 1.5228x; 1.3450x over previous
//
#include <hip/hip_runtime.h>
#include <math.h>

#define HID 64
#define KIN 512

typedef __attribute__((ext_vector_type(8))) short short8;   // 8 bf16 (4 VGPR)
typedef __attribute__((ext_vector_type(4))) float floatx4;  // MFMA acc

// RNE fp32 -> bf16
__device__ inline unsigned bf16pair(float a, float b) {
  unsigned ua = __float_as_uint(a);
  unsigned ub = __float_as_uint(b);
  ua = (ua + 0x7FFFu + ((ua >> 16) & 1u)) >> 16;
  ub = (ub + 0x7FFFu + ((ub >> 16) & 1u)) >> 16;
  return ua | (ub << 16);
}
__device__ inline unsigned short bf16one(float a) {
  unsigned ua = __float_as_uint(a);
  return (unsigned short)((ua + 0x7FFFu + ((ua >> 16) & 1u)) >> 16);
}
__device__ inline float bflo(unsigned u) { return __uint_as_float(u << 16); }
__device__ inline float bfhi(unsigned u) {
  return __uint_as_float(u & 0xffff0000u);
}

// ---- one-time weight prep: transpose + bf16 ----
__global__ __launch_bounds__(256) void prep_kernel(
    const float* __restrict__ We, const float* __restrict__ Wl,
    const float* __restrict__ Wr, unsigned short* __restrict__ wte,
    unsigned short* __restrict__ wlrt) {
  const int blk = blockIdx.x;
  const int tid = threadIdx.x;
  if (blk < 128) {
    const int t = blk * 256 + tid;
    const int c = t >> 9, k = t & 511;
    wte[c * KIN + k] = bf16one(We[k * HID + c]);
  } else {
    const int t = (blk - 128) * 256 + tid;  // 0..24575
    const int mat = t >> 12;                // 0..5
    const int e = t & 4095;
    const int c = e >> 6, k = e & 63;
    const float* src =
        (mat < 3) ? (Wl + (size_t)mat * 4096) : (Wr + (size_t)(mat - 3) * 4096);
    wlrt[(size_t)mat * 4096 + c * 64 + k] = bf16one(src[k * 64 + c]);
  }
}

// ---- encoder: hb = bf16(x @ W_enc + b_enc) via MFMA ----
__global__ __launch_bounds__(256) void enc_kernel(
    const float* __restrict__ x, const unsigned short* __restrict__ wt,
    const float* __restrict__ b, unsigned short* __restrict__ hb, int N) {
  __shared__ uint4 sx[2][256];
  __shared__ uint4 sw[2][256];
  const int t = threadIdx.x;
  const int lane = t & 63;
  const int wid = t >> 6;
  const int m15 = lane & 15;
  const int quad = lane >> 4;
  const int blockBase = blockIdx.x * 64;

  const int rs = t >> 2;
  const int qs = t & 3;
  const int us = rs * 4 + (qs ^ ((rs >> 1) & 3));
  const int gn = blockBase + rs;
  const bool valid = gn < N;
  const float* xp = x + (size_t)(valid ? gn : 0) * KIN + qs * 8;
  const unsigned short* wp = wt + (size_t)rs * KIN + qs * 8;

  const int arow = wid * 16 + m15;
  const int ua = arow * 4 + (quad ^ ((arow >> 1) & 3));
  int ub[4];
#pragma unroll
  for (int c4 = 0; c4 < 4; c4++) {
    const int col = c4 * 16 + m15;
    ub[c4] = col * 4 + (quad ^ ((col >> 1) & 3));
  }

  floatx4 acc[4];
#pragma unroll
  for (int c4 = 0; c4 < 4; c4++)
#pragma unroll
    for (int j = 0; j < 4; j++) acc[c4][j] = 0.f;

  float4 fx0, fx1;
  uint4 wv;
  if (valid) {
    fx0 = *(const float4*)(xp);
    fx1 = *(const float4*)(xp + 4);
  } else {
    fx0 = fx1 = make_float4(0.f, 0.f, 0.f, 0.f);
  }
  wv = *(const uint4*)(wp);

  for (int kc = 0; kc < 16; kc++) {
    const int cur = kc & 1;
    uint4 xu;
    xu.x = bf16pair(fx0.x, fx0.y);
    xu.y = bf16pair(fx0.z, fx0.w);
    xu.z = bf16pair(fx1.x, fx1.y);
    xu.w = bf16pair(fx1.z, fx1.w);
    sx[cur][us] = xu;
    sw[cur][us] = wv;
    __syncthreads();
    if (kc < 15) {
      const int ko = (kc + 1) * 32;
      if (valid) {
        fx0 = *(const float4*)(xp + ko);
        fx1 = *(const float4*)(xp + ko + 4);
      }
      wv = *(const uint4*)(wp + ko);
    }
    const short8 a = __builtin_bit_cast(short8, sx[cur][ua]);
#pragma unroll
    for (int c4 = 0; c4 < 4; c4++) {
      const short8 bf = __builtin_bit_cast(short8, sw[cur][ub[c4]]);
      acc[c4] =
          __builtin_amdgcn_mfma_f32_16x16x32_bf16(a, bf, acc[c4], 0, 0, 0);
    }
  }

#pragma unroll
  for (int c4 = 0; c4 < 4; c4++) {
    const float bias = b[c4 * 16 + m15];
#pragma unroll
    for (int r = 0; r < 4; r++) {
      const int row = blockBase + wid * 16 + quad * 4 + r;
      if (row < N)
        hb[(size_t)row * HID + c4 * 16 + m15] = bf16one(acc[c4][r] + bias);
    }
  }
}

// ---------------- degree histogram ----------------
__global__ void hist_kernel(const int* __restrict__ dst, int* __restrict__ cnt,
                            int E, int N) {
  int e = blockIdx.x * blockDim.x + threadIdx.x;
  if (e < E) {
    int d = dst[e];
    if ((unsigned)d < (unsigned)N) atomicAdd(&cnt[d], 1);
  }
}

// ---------------- parallel scan ----------------
__global__ __launch_bounds__(1024) void scanA_kernel(
    const int* __restrict__ cnt, int* __restrict__ block_sums, int N) {
  __shared__ int red[1024];
  const int tid = threadIdx.x;
  const int i = blockIdx.x * 1024 + tid;
  red[tid] = (i < N) ? cnt[i] : 0;
  __syncthreads();
  for (int off = 512; off > 0; off >>= 1) {
    if (tid < off) red[tid] += red[tid + off];
    __syncthreads();
  }
  if (tid == 0) block_sums[blockIdx.x] = red[0];
}

__global__ __launch_bounds__(128) void scanB_kernel(
    int* __restrict__ block_sums, int* __restrict__ row_start, int nblk,
    int N) {
  __shared__ int part[128];
  const int tid = threadIdx.x;
  part[tid] = (tid < nblk) ? block_sums[tid] : 0;
  __syncthreads();
  for (int off = 1; off < 128; off <<= 1) {
    int t = (tid >= off) ? part[tid - off] : 0;
    __syncthreads();
    part[tid] += t;
    __syncthreads();
  }
  if (tid < nblk) block_sums[tid] = (tid > 0) ? part[tid - 1] : 0;
  if (tid == 127) row_start[N] = part[127];
}

__global__ __launch_bounds__(1024) void scanC_kernel(
    const int* __restrict__ cnt, const int* __restrict__ block_sums,
    int* __restrict__ row_start, float* __restrict__ inv_deg, int N) {
  __shared__ int part[1024];
  const int tid = threadIdx.x;
  const int i = blockIdx.x * 1024 + tid;
  const int v = (i < N) ? cnt[i] : 0;
  part[tid] = v;
  __syncthreads();
  for (int off = 1; off < 1024; off <<= 1) {
    int t = (tid >= off) ? part[tid - off] : 0;
    __syncthreads();
    part[tid] += t;
    __syncthreads();
  }
  if (i < N) {
    row_start[i] = block_sums[blockIdx.x] + part[tid] - v;
    inv_deg[i] = (v > 0) ? 1.0f / (float)v : 0.0f;
  }
}

// ---------------- bucket edges by dst (CSR) ----------------
__global__ void scatter_kernel(const int* __restrict__ src,
                               const int* __restrict__ dst,
                               const int* __restrict__ row_start,
                               int* __restrict__ cursor,
                               int* __restrict__ csr_src, int E, int N) {
  int e = blockIdx.x * blockDim.x + threadIdx.x;
  if (e < E) {
    int d = dst[e];
    if ((unsigned)d < (unsigned)N) {
      int pos = row_start[d] + atomicAdd(&cursor[d], 1);
      int s = src[e];
      if ((unsigned)s >= (unsigned)N) s = 0;
      csr_src[pos] = s;
    }
  }
}

// ===== fused layer: gather-mean -> [agg|h]@[Wl;Wr] MFMA -> residual/relu
//       -> bf16 store (+ optional classifier on last layer) =====
// Gather: lane=(slot 0..7, oct 0..7). Slot owns a node; its 8 lanes read the
// full 128B h row as uint4 each. Edge loop unrolled x4 (4 idx loads then 4
// independent gathers) -> 32 gathers in flight per wave, no shfl reduce.
__global__ __launch_bounds__(256) void layer_kernel(
    const unsigned short* __restrict__ hin, unsigned short* __restrict__ hout,
    const int* __restrict__ row_start, const int* __restrict__ csr_src,
    const float* __restrict__ inv_deg, const unsigned short* __restrict__ Wlt,
    const unsigned short* __restrict__ Wrt, const float* __restrict__ bl,
    const float* __restrict__ Wc, const float* __restrict__ bc,
    float* __restrict__ out, int N) {
  __shared__ uint4 sAgg[512];  // 8 KB agg tile
  __shared__ uint4 sH[512];    // 8 KB own h rows
  __shared__ uint4 sWl[512];   // 8 KB Wl^T bf16
  __shared__ uint4 sWr[512];   // 8 KB Wr^T bf16
  const int tid = threadIdx.x;
  const int lane = tid & 63;
  const int wid = tid >> 6;
  const int m15 = lane & 15;
  const int quad = lane >> 4;
  const int blockBase = blockIdx.x * 64;

  // ---- stage own h rows + both weight mats ----
  {
    const int r = tid >> 2;
    const int gp = tid & 3;
    const int g0 = gp * 2, g1 = gp * 2 + 1;
    const int u0 = r * 8 + (g0 ^ (r & 7));
    const int u1 = r * 8 + (g1 ^ (r & 7));
    const int gn = blockBase + r;
    if (gn < N) {
      const uint4* hp = (const uint4*)(hin + (size_t)gn * HID);
      sH[u0] = hp[g0];
      sH[u1] = hp[g1];
    } else {
      const uint4 z = make_uint4(0, 0, 0, 0);
      sH[u0] = z;
      sH[u1] = z;
    }
    const uint4* wl = (const uint4*)(Wlt + (size_t)r * HID);
    const uint4* wr = (const uint4*)(Wrt + (size_t)r * HID);
    sWl[u0] = wl[g0];
    sWl[u1] = wl[g1];
    sWr[u0] = wr[g0];
    sWr[u1] = wr[g1];
  }

  // ---- mean-aggregate neighbors into sAgg ----
  {
    const int slot = lane >> 3;  // 0..7: node slot
    const int oct = lane & 7;    // 0..7: uint4 column group (8 bf16)
#pragma unroll
    for (int g = 0; g < 2; g++) {
      const int nl = wid * 16 + g * 8 + slot;
      const int gn = blockBase + nl;
      float a0 = 0.f, a1 = 0.f, a2 = 0.f, a3 = 0.f, a4 = 0.f, a5 = 0.f,
            a6 = 0.f, a7 = 0.f;
      float id = 0.f;
      if (gn < N) {
        id = inv_deg[gn];
        const int s = row_start[gn];
        const int e = row_start[gn + 1];
        int j = s;
        for (; j + 4 <= e; j += 4) {
          const int n0 = csr_src[j];
          const int n1 = csr_src[j + 1];
          const int n2 = csr_src[j + 2];
          const int n3 = csr_src[j + 3];
          const uint4 v0 = *(const uint4*)(hin + (size_t)n0 * HID + oct * 8);
          const uint4 v1 = *(const uint4*)(hin + (size_t)n1 * HID + oct * 8);
          const uint4 v2 = *(const uint4*)(hin + (size_t)n2 * HID + oct * 8);
          const uint4 v3 = *(const uint4*)(hin + (size_t)n3 * HID + oct * 8);
          a0 += bflo(v0.x) + bflo(v1.x) + bflo(v2.x) + bflo(v3.x);
          a1 += bfhi(v0.x) + bfhi(v1.x) + bfhi(v2.x) + bfhi(v3.x);
          a2 += bflo(v0.y) + bflo(v1.y) + bflo(v2.y) + bflo(v3.y);
          a3 += bfhi(v0.y) + bfhi(v1.y) + bfhi(v2.y) + bfhi(v3.y);
          a4 += bflo(v0.z) + bflo(v1.z) + bflo(v2.z) + bflo(v3.z);
          a5 += bfhi(v0.z) + bfhi(v1.z) + bfhi(v2.z) + bfhi(v3.z);
          a6 += bflo(v0.w) + bflo(v1.w) + bflo(v2.w) + bflo(v3.w);
          a7 += bfhi(v0.w) + bfhi(v1.w) + bfhi(v2.w) + bfhi(v3.w);
        }
        for (; j < e; j++) {
          const int nb = csr_src[j];
          const uint4 v = *(const uint4*)(hin + (size_t)nb * HID + oct * 8);
          a0 += bflo(v.x);
          a1 += bfhi(v.x);
          a2 += bflo(v.y);
          a3 += bfhi(v.y);
          a4 += bflo(v.z);
          a5 += bfhi(v.z);
          a6 += bflo(v.w);
          a7 += bfhi(v.w);
        }
      }
      uint4 p;
      p.x = bf16pair(a0 * id, a1 * id);
      p.y = bf16pair(a2 * id, a3 * id);
      p.z = bf16pair(a4 * id, a5 * id);
      p.w = bf16pair(a6 * id, a7 * id);
      sAgg[nl * 8 + (oct ^ (nl & 7))] = p;
    }
  }
  __syncthreads();

  // ---- MFMA: acc = agg@Wl + h@Wr ----
  floatx4 acc[4];
#pragma unroll
  for (int c4 = 0; c4 < 4; c4++)
#pragma unroll
    for (int j = 0; j < 4; j++) acc[c4][j] = 0.f;

  const int arow = wid * 16 + m15;
#pragma unroll
  for (int c = 0; c < 2; c++) {
    const int ua = arow * 8 + ((c * 4 + quad) ^ (arow & 7));
    const short8 aA = __builtin_bit_cast(short8, sAgg[ua]);
    const short8 aH = __builtin_bit_cast(short8, sH[ua]);
#pragma unroll
    for (int c4 = 0; c4 < 4; c4++) {
      const int col = c4 * 16 + m15;
      const int ub = col * 8 + ((c * 4 + quad) ^ (col & 7));
      acc[c4] = __builtin_amdgcn_mfma_f32_16x16x32_bf16(
          aA, __builtin_bit_cast(short8, sWl[ub]), acc[c4], 0, 0, 0);
      acc[c4] = __builtin_amdgcn_mfma_f32_16x16x32_bf16(
          aH, __builtin_bit_cast(short8, sWr[ub]), acc[c4], 0, 0, 0);
    }
  }

  // ---- epilogue: residual + bias + relu; bf16 store; optional cls ----
  float vals[4][4];
#pragma unroll
  for (int c4 = 0; c4 < 4; c4++) {
    const float bias = bl[c4 * 16 + m15];
#pragma unroll
    for (int r = 0; r < 4; r++) {
      const int rowl = wid * 16 + quad * 4 + r;
      const unsigned short hv =
          ((const unsigned short*)
               sH)[(rowl * 8 + ((c4 * 2 + (m15 >> 3)) ^ (rowl & 7))) * 8 +
                   (m15 & 7)];
      const float v = __uint_as_float((unsigned)hv << 16) + acc[c4][r] + bias;
      vals[c4][r] = v > 0.f ? v : 0.f;
    }
  }
#pragma unroll
  for (int c4 = 0; c4 < 4; c4++) {
#pragma unroll
    for (int r = 0; r < 4; r++) {
      const int rowg = blockBase + wid * 16 + quad * 4 + r;
      if (rowg < N)
        hout[(size_t)rowg * HID + c4 * 16 + m15] = bf16one(vals[c4][r]);
    }
  }
  if (Wc != nullptr) {
    float p[4] = {0.f, 0.f, 0.f, 0.f};
#pragma unroll
    for (int c4 = 0; c4 < 4; c4++) {
      const float wc = Wc[c4 * 16 + m15];
#pragma unroll
      for (int r = 0; r < 4; r++) p[r] += vals[c4][r] * wc;
    }
#pragma unroll
    for (int off = 1; off < 16; off <<= 1) {
#pragma unroll
      for (int r = 0; r < 4; r++) p[r] += __shfl_xor(p[r], off, 16);
    }
    if (m15 == 0) {
      const float bb = bc[0];
#pragma unroll
      for (int r = 0; r < 4; r++) {
        const int rowg = blockBase + wid * 16 + quad * 4 + r;
        if (rowg < N) out[rowg] = 1.0f / (1.0f + expf(-(p[r] + bb)));
      }
    }
  }
}

extern "C" void kernel_launch(void* const* d_in, const int* in_sizes, int n_in,
                              void* d_out, int out_size, void* d_ws,
                              size_t ws_size, hipStream_t stream) {
  const float* x = (const float*)d_in[0];
  const int* ei = (const int*)d_in[1];
  const float* W_enc = (const float*)d_in[2];
  const float* b_enc = (const float*)d_in[3];
  const float* Wl = (const float*)d_in[4];
  const float* bl = (const float*)d_in[5];
  const float* Wr = (const float*)d_in[6];
  const float* Wc = (const float*)d_in[7];
  const float* bc = (const float*)d_in[8];
  float* out = (float*)d_out;

  const int N = in_sizes[0] / KIN;
  const int E = in_sizes[1] / 2;
  const int* src = ei;
  const int* dst = ei + E;

  char* ws = (char*)d_ws;
  size_t off = 0;
  auto alloc = [&](size_t bytes) -> void* {
    void* p = ws + off;
    off += (bytes + 255) & ~(size_t)255;
    return p;
  };
  unsigned short* hb0 =
      (unsigned short*)alloc((size_t)N * HID * sizeof(unsigned short));
  unsigned short* hb1 =
      (unsigned short*)alloc((size_t)N * HID * sizeof(unsigned short));
  int* cnt = (int*)alloc((size_t)N * sizeof(int));
  int* row_start = (int*)alloc((size_t)(N + 1) * sizeof(int));
  int* cursor = (int*)alloc((size_t)N * sizeof(int));
  float* inv_deg = (float*)alloc((size_t)N * sizeof(float));
  int* csr_src = (int*)alloc((size_t)E * sizeof(int));
  const int nblk = (N + 1023) / 1024;
  int* block_sums = (int*)alloc((size_t)nblk * sizeof(int));
  unsigned short* wte =
      (unsigned short*)alloc((size_t)HID * KIN * sizeof(unsigned short));
  unsigned short* wlrt =
      (unsigned short*)alloc((size_t)6 * HID * HID * sizeof(unsigned short));

  hipMemsetAsync(cnt, 0, (size_t)N * sizeof(int), stream);
  hipMemsetAsync(cursor, 0, (size_t)N * sizeof(int), stream);

  prep_kernel<<<224, 256, 0, stream>>>(W_enc, Wl, Wr, wte, wlrt);
  hist_kernel<<<(E + 255) / 256, 256, 0, stream>>>(dst, cnt, E, N);
  scanA_kernel<<<nblk, 1024, 0, stream>>>(cnt, block_sums, N);
  scanB_kernel<<<1, 128, 0, stream>>>(block_sums, row_start, nblk, N);
  scanC_kernel<<<nblk, 1024, 0, stream>>>(cnt, block_sums, row_start, inv_deg,
                                          N);
  scatter_kernel<<<(E + 255) / 256, 256, 0, stream>>>(src, dst, row_start,
                                                      cursor, csr_src, E, N);
  enc_kernel<<<(N + 63) / 64, 256, 0, stream>>>(x, wte, b_enc, hb0, N);

  const int nb64 = (N + 63) / 64;
  // layer 0: hb0 -> hb1
  layer_kernel<<<nb64, 256, 0, stream>>>(hb0, hb1, row_start, csr_src, inv_deg,
                                         wlrt, wlrt + 3 * 4096, bl, nullptr,
                                         nullptr, nullptr, N);
  // layer 1: hb1 -> hb0
  layer_kernel<<<nb64, 256, 0, stream>>>(hb1, hb0, row_start, csr_src, inv_deg,
                                         wlrt + 4096, wlrt + 4 * 4096, bl + 64,
                                         nullptr, nullptr, nullptr, N);
  // layer 2: hb0 -> hb1, fused classifier
  layer_kernel<<<nb64, 256, 0, stream>>>(hb0, hb1, row_start, csr_src, inv_deg,
                                         wlrt + 2 * 4096, wlrt + 5 * 4096,
                                         bl + 128, Wc, bc, out, N);
}